// Round 1
// baseline (589.985 us; speedup 1.0000x reference)
//
#include <hip/hip_runtime.h>
#include <stdint.h>

// GCN pipeline on MI355X. Factorization:
//   (m/deg)@msg = diag(rsqrt(rd)) * m_bf16 @ (diag(rsqrt(cd))*msg)
// R4: k_gemm -> 2-phase double-buffered prefetch (one barrier/iter, catalog
// T3-minimum), SPLITK 8->16 (grid 1024, fills the 3-blocks/CU occupancy).
// New k_red: coalesced split-K reduce with rsqrt(rd) folded -> dense h (4MB);
// k_msg layer2 reads h (no strided 16-way gather), pool+classify fused.
//   k_cast     : m fp32 (256MB) -> mb bf16 (128MB), rd row sums
//   k_cd       : column sums of mb (L3-hot) into 256 slice partials
//   k_cd2      : reduce slices -> cd
//   k_msg      : msgT[n][j] = bf16(relu(src[j]@W[n]+b[n]) * rsqrt(cd[j]))  (MFMA)
//   k_gemm     : split-K=16 bf16 MFMA GEMM, dbuf LDS + global_load_lds w16
//   k_red      : h[i][:] = rsqrt(rd[i]) * sum_p part[p][i][:]   (coalesced)
//   k_poolcls  : per-graph max over h + 16-class linear

#define NN 8192
#define DH 128
#define NCLS 16
#define NGRAPH 64
#define SPLITK 16
#define KCHUNK (NN / SPLITK) // 512
#define CDSLICE 256          // k_cd row slices (32 rows each)

typedef float floatx4 __attribute__((ext_vector_type(4)));
typedef __bf16 bf16x8 __attribute__((ext_vector_type(8)));

__device__ __forceinline__ unsigned f2bf_bits(float f) {
    union { float f; unsigned u; } v; v.f = f;
    unsigned u = v.u;
    u += 0x7fffu + ((u >> 16) & 1u);   // RNE
    return u >> 16;
}
__device__ __forceinline__ float bf2f(unsigned bits16) {
    union { unsigned u; float f; } v; v.u = bits16 << 16; return v.f;
}

__device__ __forceinline__ void gload16(const void* g, void* l) {
    __builtin_amdgcn_global_load_lds(
        (const __attribute__((address_space(1))) void*)g,
        (__attribute__((address_space(3))) void*)l, 16, 0, 0);
}

// ---- m fp32 -> mb bf16, rd row sums. 1 row per wave, pure sequential stream.
__global__ __launch_bounds__(256) void k_cast(
    const float* __restrict__ m, unsigned short* __restrict__ mb,
    float* __restrict__ rd)
{
    int wv = threadIdx.x >> 6, lane = threadIdx.x & 63;
    int row = blockIdx.x * 4 + wv;
    const float* src = m + (size_t)row * NN;
    unsigned short* dst = mb + (size_t)row * NN;
    float rsum = 0.f;
#pragma unroll 4
    for (int it = 0; it < 32; ++it) {
        int c = it * 256 + lane * 4;
        float4 a = *(const float4*)(src + c);
        rsum += (a.x + a.y) + (a.z + a.w);
        uint2 o;
        o.x = f2bf_bits(a.x) | (f2bf_bits(a.y) << 16);
        o.y = f2bf_bits(a.z) | (f2bf_bits(a.w) << 16);
        *(uint2*)(dst + c) = o;
    }
#pragma unroll
    for (int off = 1; off < 64; off <<= 1) rsum += __shfl_xor(rsum, off, 64);
    if (lane == 0) rd[row] = rsum;
}

// ---- column partial sums of mb (L3-hot). block = 2048 cols x 32 rows, grid 1024.
__global__ __launch_bounds__(256) void k_cd(
    const unsigned short* __restrict__ mb, float* __restrict__ cdpart)
{
    int cb = blockIdx.x & 3, rb = blockIdx.x >> 2;     // rb 0..255
    int c = cb * 2048 + threadIdx.x * 8;
    const unsigned short* p = mb + (size_t)rb * 32 * NN + c;
    float s[8];
#pragma unroll
    for (int u = 0; u < 8; ++u) s[u] = 0.f;
#pragma unroll 4
    for (int r = 0; r < 32; ++r) {
        uint4 v = *(const uint4*)(p + (size_t)r * NN);
        s[0] += bf2f(v.x & 0xffffu); s[1] += bf2f(v.x >> 16);
        s[2] += bf2f(v.y & 0xffffu); s[3] += bf2f(v.y >> 16);
        s[4] += bf2f(v.z & 0xffffu); s[5] += bf2f(v.z >> 16);
        s[6] += bf2f(v.w & 0xffffu); s[7] += bf2f(v.w >> 16);
    }
    float* op = cdpart + (size_t)rb * NN + c;
    *(float4*)op = (float4){s[0], s[1], s[2], s[3]};
    *(float4*)(op + 4) = (float4){s[4], s[5], s[6], s[7]};
}

__global__ __launch_bounds__(256) void k_cd2(
    const float* __restrict__ cdpart, float* __restrict__ cd)
{
    int col = blockIdx.x * 256 + threadIdx.x;
    float s = 0.f;
#pragma unroll 8
    for (int r = 0; r < CDSLICE; ++r) s += cdpart[(size_t)r * NN + col];
    cd[col] = s;
}

// ---- msgT[n][j] = bf16( relu( src[j]@W[n] + b[n] ) * rsqrt(cd[j]) )
// src = emb[x[j]] (layer 1) or h[j] (layer 2, rd-scale already folded by k_red).
// One wave per block (64 threads), 16 j per block, grid 512.
__global__ __launch_bounds__(64) void k_msg(
    const int* __restrict__ x, const float* __restrict__ emb,
    const float* __restrict__ hsrc,
    const float* __restrict__ w, const float* __restrict__ bias,
    const float* __restrict__ cdv, unsigned short* __restrict__ msgT,
    int layer)
{
    int lane = threadIdx.x & 63;
    int quad = lane >> 4, r16 = lane & 15;
    int j = blockIdx.x * 16 + r16;

    floatx4 acc[8];
#pragma unroll
    for (int t = 0; t < 8; ++t) acc[t] = (floatx4)0.f;

    const float* src;
    if (layer == 1) src = emb + (size_t)x[j] * DH;
    else            src = hsrc + (size_t)j * DH;

#pragma unroll
    for (int e0 = 0; e0 < DH; e0 += 32) {
        int ke = e0 + quad * 8;
        float4 a = *(const float4*)(src + ke);
        float4 b = *(const float4*)(src + ke + 4);
        bf16x8 bfv;
        bfv[0] = (__bf16)a.x; bfv[1] = (__bf16)a.y; bfv[2] = (__bf16)a.z; bfv[3] = (__bf16)a.w;
        bfv[4] = (__bf16)b.x; bfv[5] = (__bf16)b.y; bfv[6] = (__bf16)b.z; bfv[7] = (__bf16)b.w;
#pragma unroll
        for (int t = 0; t < 8; ++t) {
            const float* wp = w + (size_t)(t * 16 + r16) * DH + ke;
            float4 wa = *(const float4*)wp;
            float4 wb = *(const float4*)(wp + 4);
            bf16x8 af;
            af[0] = (__bf16)wa.x; af[1] = (__bf16)wa.y; af[2] = (__bf16)wa.z; af[3] = (__bf16)wa.w;
            af[4] = (__bf16)wb.x; af[5] = (__bf16)wb.y; af[6] = (__bf16)wb.z; af[7] = (__bf16)wb.w;
            acc[t] = __builtin_amdgcn_mfma_f32_16x16x32_bf16(af, bfv, acc[t], 0, 0, 0);
        }
    }
    float cs = rsqrtf(cdv[j]);
#pragma unroll
    for (int t = 0; t < 8; ++t) {
#pragma unroll
        for (int r = 0; r < 4; ++r) {
            int n = t * 16 + quad * 4 + r;
            float val = acc[t][r] + bias[n];
            val = fmaxf(val, 0.f) * cs;
            msgT[(size_t)n * NN + j] = (unsigned short)f2bf_bits(val);
        }
    }
}

// ---- part[kp][i][n] = sum_{k in chunk kp} A[i][k] * Bt[n][k]
// BM=128, BN=128, BK=32, 4 waves of 64x64. 2-phase double-buffered LDS:
// prefetch tile t+1 (global_load_lds w16) before computing tile t; ONE
// __syncthreads per iter (drains vmcnt for the prefetch + lgkm for ds_reads).
__global__ __launch_bounds__(256) void k_gemm(
    const unsigned short* __restrict__ A,   // 8192 x 8192 bf16 row-major
    const unsigned short* __restrict__ Bt,  // 128 x 8192 bf16 (N x K)
    float* __restrict__ part)               // SPLITK x 8192 x 128
{
    __shared__ unsigned short lA[2][128 * 32];
    __shared__ unsigned short lB[2][128 * 32];
    int mblk = blockIdx.x & 63;
    int kp = blockIdx.x >> 6;
    int tid = threadIdx.x;
    int wv = tid >> 6, lane = tid & 63;
    int quad = lane >> 4, r16 = lane & 15;
    int wm = wv >> 1, wn = wv & 1;
    size_t mbase = (size_t)mblk * 128;
    int kbase = kp * KCHUNK;

    floatx4 acc[4][4];
#pragma unroll
    for (int mi = 0; mi < 4; ++mi)
#pragma unroll
        for (int ni = 0; ni < 4; ++ni) acc[mi][ni] = (floatx4)0.f;

    int srow = lane >> 2;   // 0..15
    int kq = lane & 3;      // 16B chunk within 64B row
    const unsigned short* gA = A + (mbase + wv * 32 + srow) * (size_t)NN + kbase + kq * 8;
    const unsigned short* gB = Bt + (size_t)(wv * 32 + srow) * NN + kbase + kq * 8;

    // prologue: stage tile 0 into buffer 0
    {
        char* lAw = (char*)lA[0] + wv * 2048;
        char* lBw = (char*)lB[0] + wv * 2048;
        gload16(gA, lAw);
        gload16(gA + (size_t)16 * NN, lAw + 1024);
        gload16(gB, lBw);
        gload16(gB + (size_t)16 * NN, lBw + 1024);
        gA += 32; gB += 32;
    }
    __syncthreads();

    constexpr int NIT = KCHUNK / 32;  // 16
#pragma unroll 2
    for (int it = 0; it < NIT; ++it) {
        int cur = it & 1;
        if (it + 1 < NIT) {             // prefetch next tile into other buffer
            char* lAw = (char*)lA[cur ^ 1] + wv * 2048;
            char* lBw = (char*)lB[cur ^ 1] + wv * 2048;
            gload16(gA, lAw);
            gload16(gA + (size_t)16 * NN, lAw + 1024);
            gload16(gB, lBw);
            gload16(gB + (size_t)16 * NN, lBw + 1024);
            gA += 32; gB += 32;
        }
        const char* cA = (const char*)lA[cur];
        const char* cB = (const char*)lB[cur];
        bf16x8 af[4], bf[4];
#pragma unroll
        for (int mi = 0; mi < 4; ++mi)
            af[mi] = *(const bf16x8*)(cA + ((wm * 64 + mi * 16 + r16) * 64 + quad * 16));
#pragma unroll
        for (int ni = 0; ni < 4; ++ni)
            bf[ni] = *(const bf16x8*)(cB + ((wn * 64 + ni * 16 + r16) * 64 + quad * 16));
#pragma unroll
        for (int mi = 0; mi < 4; ++mi)
#pragma unroll
            for (int ni = 0; ni < 4; ++ni)
                acc[mi][ni] = __builtin_amdgcn_mfma_f32_16x16x32_bf16(af[mi], bf[ni], acc[mi][ni], 0, 0, 0);
        __syncthreads();                // next buffer staged + cur reads done
    }

    float* outp = part + (size_t)kp * ((size_t)NN * DH);
#pragma unroll
    for (int mi = 0; mi < 4; ++mi) {
#pragma unroll
        for (int r = 0; r < 4; ++r) {
            size_t i = mbase + wm * 64 + mi * 16 + quad * 4 + r;
            float* op = outp + i * DH + wn * 64 + r16;
#pragma unroll
            for (int ni = 0; ni < 4; ++ni) op[ni * 16] = acc[mi][ni][r];
        }
    }
}

// ---- h[i][c] = rsqrt(rd[i]) * sum_p part[p][i][c]. Coalesced float4.
// block = 8 rows x 128 cols, grid 1024.
__global__ __launch_bounds__(256) void k_red(
    const float* __restrict__ part, const float* __restrict__ rdv,
    float* __restrict__ h)
{
    int i = blockIdx.x * 8 + (threadIdx.x >> 5);
    int c4 = (threadIdx.x & 31) * 4;
    size_t off = (size_t)i * DH + c4;
    float4 s = (float4){0.f, 0.f, 0.f, 0.f};
#pragma unroll
    for (int p = 0; p < SPLITK; ++p) {
        float4 v = *(const float4*)(part + (size_t)p * ((size_t)NN * DH) + off);
        s.x += v.x; s.y += v.y; s.z += v.z; s.w += v.w;
    }
    float sc = rsqrtf(rdv[i]);
    s.x *= sc; s.y *= sc; s.z *= sc; s.w *= sc;
    *(float4*)(h + off) = s;
}

// ---- per-graph max over 128 rows of h (4MB) + 16-class linear. grid 64.
__global__ __launch_bounds__(256) void k_poolcls(
    const float* __restrict__ h, const float* __restrict__ wc,
    const float* __restrict__ bc, float* __restrict__ out)
{
    __shared__ float red[256];
    __shared__ float pooled[128];
    int g = blockIdx.x;
    int c = threadIdx.x & 127, rh = threadIdx.x >> 7;
    float mx = -1e30f;
#pragma unroll 8
    for (int r = 0; r < 64; ++r) {
        int i = g * 128 + rh * 64 + r;
        mx = fmaxf(mx, h[(size_t)i * DH + c]);
    }
    red[threadIdx.x] = mx;
    __syncthreads();
    if (rh == 0) pooled[c] = fmaxf(red[c], red[c + 128]);
    __syncthreads();
    if (threadIdx.x < NCLS) {
        float a = bc[threadIdx.x];
        const float* wr = wc + threadIdx.x * 128;
#pragma unroll 8
        for (int k = 0; k < 128; ++k) a += pooled[k] * wr[k];
        out[g * NCLS + threadIdx.x] = a;
    }
}

extern "C" void kernel_launch(void* const* d_in, const int* in_sizes, int n_in,
                              void* d_out, int out_size, void* d_ws, size_t ws_size,
                              hipStream_t stream)
{
    const int*   x   = (const int*)  d_in[0];
    const float* m   = (const float*)d_in[1];
    // d_in[2] = bm: (i*64)//8192 -> 128 consecutive rows per graph (fixed by setup)
    const float* emb = (const float*)d_in[3];
    const float* w1  = (const float*)d_in[4];
    const float* b1  = (const float*)d_in[5];
    const float* w2  = (const float*)d_in[6];
    const float* b2  = (const float*)d_in[7];
    const float* wc  = (const float*)d_in[8];
    const float* bc  = (const float*)d_in[9];
    float* out = (float*)d_out;

    char* ws = (char*)d_ws;
    unsigned short* mb = (unsigned short*)ws;                         // 128 MB
    float* rd   = (float*)(ws + (size_t)134217728);                   // 32 KB
    float* cd   = rd + NN;                                            // 32 KB
    unsigned short* msgT = (unsigned short*)(cd + NN);                // 2 MB
    float* part = (float*)((char*)msgT + (size_t)2 * NN * DH);        // 64 MB
    float* cdpart = part;      // aliased: cdpart used only before first k_gemm
    float* h    = part + (size_t)SPLITK * NN * DH;                    // 4 MB

    k_cast<<<NN / 4, 256, 0, stream>>>(m, mb, rd);
    k_cd<<<1024, 256, 0, stream>>>(mb, cdpart);
    k_cd2<<<NN / 256, 256, 0, stream>>>(cdpart, cd);
    k_msg<<<NN / 16, 64, 0, stream>>>(x, emb, nullptr, w1, b1, cd, msgT, 1);
    k_gemm<<<64 * SPLITK, 256, 0, stream>>>(mb, msgT, part);
    k_red<<<NN / 8, 256, 0, stream>>>(part, rd, h);
    k_msg<<<NN / 16, 64, 0, stream>>>(nullptr, nullptr, h, w2, b2, cd, msgT, 2);
    k_gemm<<<64 * SPLITK, 256, 0, stream>>>(mb, msgT, part);
    k_red<<<NN / 8, 256, 0, stream>>>(part, rd, h);
    k_poolcls<<<NGRAPH, 256, 0, stream>>>(h, wc, bc, out);
}

// Round 2
// 536.609 us; speedup vs baseline: 1.0995x; 1.0995x over previous
//
#include <hip/hip_runtime.h>
#include <stdint.h>

// GCN pipeline on MI355X. Factorization:
//   (m/deg)@msg = diag(rsqrt(rd)) * m_bf16 @ (diag(rsqrt(cd))*msg)
// R5: gemm reverted to R0's proven single-buffer structure (SPLITK=8; R4's
// dbuf+SPLITK16 regressed +50us: doubled part traffic + per-iter vmcnt drain).
// k_cd FUSED into k_cast (register-private column partials; kills the 128MB
// mb re-read). k_msg split across 2 waves (occupancy 2x). k_red/poolcls kept.
//   k_castcd   : m fp32 -> mb bf16, rd row sums, cdpart col partials (512 slabs)
//   k_cd2      : reduce 512 slabs -> cd
//   k_msg      : msgT[n][j] = bf16(relu(src[j]@W[n]+b[n]) * rsqrt(cd[j]))  (MFMA)
//   k_gemm     : split-K=8 bf16 MFMA GEMM (m97 structure, global_load_lds w16)
//   k_red      : h[i][:] = rsqrt(rd[i]) * sum_p part[p][i][:]   (coalesced)
//   k_poolcls  : per-graph max over h + 16-class linear

#define NN 8192
#define DH 128
#define NCLS 16
#define NGRAPH 64
#define SPLITK 8
#define KCHUNK (NN / SPLITK) // 1024
#define CDSLAB 512           // col-partial slabs (16 rows each)

typedef float floatx4 __attribute__((ext_vector_type(4)));
typedef __bf16 bf16x8 __attribute__((ext_vector_type(8)));

__device__ __forceinline__ unsigned f2bf_bits(float f) {
    union { float f; unsigned u; } v; v.f = f;
    unsigned u = v.u;
    u += 0x7fffu + ((u >> 16) & 1u);   // RNE
    return u >> 16;
}

__device__ __forceinline__ void gload16(const void* g, void* l) {
    __builtin_amdgcn_global_load_lds(
        (const __attribute__((address_space(1))) void*)g,
        (__attribute__((address_space(3))) void*)l, 16, 0, 0);
}

// ---- m fp32 -> mb bf16, rd row sums, col partial sums. Block = 16 rows.
// Thread t owns cols {it*1024 + t*4 .. +3} every row -> private col regs.
__global__ __launch_bounds__(256) void k_castcd(
    const float* __restrict__ m, unsigned short* __restrict__ mb,
    float* __restrict__ rd, float* __restrict__ cdpart)
{
    __shared__ float red[256][17];   // [thread][row], 17 to kill bank conflicts
    int t = threadIdx.x;
    int rb = blockIdx.x;             // rows rb*16 .. +15
    float cs[32];
#pragma unroll
    for (int u = 0; u < 32; ++u) cs[u] = 0.f;

    for (int r = 0; r < 16; ++r) {
        const float* src = m + ((size_t)rb * 16 + r) * NN;
        unsigned short* dst = mb + ((size_t)rb * 16 + r) * NN;
        float rsum = 0.f;
#pragma unroll
        for (int it = 0; it < 8; ++it) {
            int c = it * 1024 + t * 4;
            float4 a = *(const float4*)(src + c);
            rsum += (a.x + a.y) + (a.z + a.w);
            cs[it * 4 + 0] += a.x; cs[it * 4 + 1] += a.y;
            cs[it * 4 + 2] += a.z; cs[it * 4 + 3] += a.w;
            uint2 o;
            o.x = f2bf_bits(a.x) | (f2bf_bits(a.y) << 16);
            o.y = f2bf_bits(a.z) | (f2bf_bits(a.w) << 16);
            *(uint2*)(dst + c) = o;
        }
        red[t][r] = rsum;
    }
#pragma unroll
    for (int it = 0; it < 8; ++it) {
        float4 o = (float4){cs[it * 4], cs[it * 4 + 1], cs[it * 4 + 2], cs[it * 4 + 3]};
        *(float4*)(cdpart + (size_t)rb * NN + it * 1024 + t * 4) = o;
    }
    __syncthreads();
    if (t < 16) {
        float s = 0.f;
#pragma unroll 8
        for (int u = 0; u < 256; ++u) s += red[u][t];
        rd[rb * 16 + t] = s;
    }
}

// ---- reduce 512 col-partial slabs -> cd. Block owns 32 cols, 8 slab-groups.
__global__ __launch_bounds__(256) void k_cd2(
    const float* __restrict__ cdpart, float* __restrict__ cd)
{
    __shared__ float p2[8][33];
    int c = threadIdx.x & 31, g = threadIdx.x >> 5;   // col-in-block, slab group
    int col = blockIdx.x * 32 + c;
    float s = 0.f;
#pragma unroll 8
    for (int r = 0; r < 64; ++r)
        s += cdpart[(size_t)(g * 64 + r) * NN + col];
    p2[g][c] = s;
    __syncthreads();
    if (threadIdx.x < 32) {
        float a = 0.f;
#pragma unroll
        for (int u = 0; u < 8; ++u) a += p2[u][threadIdx.x];
        cd[blockIdx.x * 32 + threadIdx.x] = a;
    }
}

// ---- msgT[n][j] = bf16( relu( src[j]@W[n] + b[n] ) * rsqrt(cd[j]) )
// src = emb[x[j]] (layer 1) or h[j] (layer 2, rd-scale folded by k_red).
// 2 waves per block: wave wv handles output tiles t = wv*4 .. wv*4+3.
__global__ __launch_bounds__(128) void k_msg(
    const int* __restrict__ x, const float* __restrict__ emb,
    const float* __restrict__ hsrc,
    const float* __restrict__ w, const float* __restrict__ bias,
    const float* __restrict__ cdv, unsigned short* __restrict__ msgT,
    int layer)
{
    int wv = threadIdx.x >> 6;
    int lane = threadIdx.x & 63;
    int quad = lane >> 4, r16 = lane & 15;
    int j = blockIdx.x * 16 + r16;

    floatx4 acc[4];
#pragma unroll
    for (int t = 0; t < 4; ++t) acc[t] = (floatx4)0.f;

    const float* src;
    if (layer == 1) src = emb + (size_t)x[j] * DH;
    else            src = hsrc + (size_t)j * DH;

#pragma unroll
    for (int e0 = 0; e0 < DH; e0 += 32) {
        int ke = e0 + quad * 8;
        float4 a = *(const float4*)(src + ke);
        float4 b = *(const float4*)(src + ke + 4);
        bf16x8 bfv;
        bfv[0] = (__bf16)a.x; bfv[1] = (__bf16)a.y; bfv[2] = (__bf16)a.z; bfv[3] = (__bf16)a.w;
        bfv[4] = (__bf16)b.x; bfv[5] = (__bf16)b.y; bfv[6] = (__bf16)b.z; bfv[7] = (__bf16)b.w;
#pragma unroll
        for (int tt = 0; tt < 4; ++tt) {
            int t = wv * 4 + tt;
            const float* wp = w + (size_t)(t * 16 + r16) * DH + ke;
            float4 wa = *(const float4*)wp;
            float4 wb = *(const float4*)(wp + 4);
            bf16x8 af;
            af[0] = (__bf16)wa.x; af[1] = (__bf16)wa.y; af[2] = (__bf16)wa.z; af[3] = (__bf16)wa.w;
            af[4] = (__bf16)wb.x; af[5] = (__bf16)wb.y; af[6] = (__bf16)wb.z; af[7] = (__bf16)wb.w;
            acc[tt] = __builtin_amdgcn_mfma_f32_16x16x32_bf16(af, bfv, acc[tt], 0, 0, 0);
        }
    }
    float cs = rsqrtf(cdv[j]);
#pragma unroll
    for (int tt = 0; tt < 4; ++tt) {
#pragma unroll
        for (int r = 0; r < 4; ++r) {
            int n = (wv * 4 + tt) * 16 + quad * 4 + r;
            float val = acc[tt][r] + bias[n];
            val = fmaxf(val, 0.f) * cs;
            msgT[(size_t)n * NN + j] = (unsigned short)f2bf_bits(val);
        }
    }
}

// ---- part[kp][i][n] = sum_{k in chunk kp} A[i][k] * Bt[n][k]
// m97 structure: BM=128, BN=128, BK=32, 4 waves of 64x64, global_load_lds w16.
__global__ __launch_bounds__(256) void k_gemm(
    const unsigned short* __restrict__ A,   // 8192 x 8192 bf16 row-major
    const unsigned short* __restrict__ Bt,  // 128 x 8192 bf16 (N x K)
    float* __restrict__ part)               // SPLITK x 8192 x 128
{
    __shared__ unsigned short lA[128 * 32];
    __shared__ unsigned short lB[128 * 32];
    int mblk = blockIdx.x & 63;
    int kp = blockIdx.x >> 6;
    int tid = threadIdx.x;
    int wv = tid >> 6, lane = tid & 63;
    int quad = lane >> 4, r16 = lane & 15;
    int wm = wv >> 1, wn = wv & 1;
    size_t mbase = (size_t)mblk * 128;
    int kbase = kp * KCHUNK;

    floatx4 acc[4][4];
#pragma unroll
    for (int mi = 0; mi < 4; ++mi)
#pragma unroll
        for (int ni = 0; ni < 4; ++ni) acc[mi][ni] = (floatx4)0.f;

    int srow = lane >> 2;   // 0..15
    int kq = lane & 3;      // 16B chunk within 64B row
    const unsigned short* gA = A + (mbase + wv * 32 + srow) * (size_t)NN + kbase + kq * 8;
    const unsigned short* gB = Bt + (size_t)(wv * 32 + srow) * NN + kbase + kq * 8;
    char* lAw = (char*)lA + wv * 2048;
    char* lBw = (char*)lB + wv * 2048;

    for (int it = 0; it < KCHUNK / 32; ++it) {
        gload16(gA, lAw);
        gload16(gA + (size_t)16 * NN, lAw + 1024);
        gload16(gB, lBw);
        gload16(gB + (size_t)16 * NN, lBw + 1024);
        __syncthreads();
        bf16x8 af[4], bf[4];
#pragma unroll
        for (int mi = 0; mi < 4; ++mi)
            af[mi] = *(const bf16x8*)((const char*)lA + ((wm * 64 + mi * 16 + r16) * 64 + quad * 16));
#pragma unroll
        for (int ni = 0; ni < 4; ++ni)
            bf[ni] = *(const bf16x8*)((const char*)lB + ((wn * 64 + ni * 16 + r16) * 64 + quad * 16));
#pragma unroll
        for (int mi = 0; mi < 4; ++mi)
#pragma unroll
            for (int ni = 0; ni < 4; ++ni)
                acc[mi][ni] = __builtin_amdgcn_mfma_f32_16x16x32_bf16(af[mi], bf[ni], acc[mi][ni], 0, 0, 0);
        __syncthreads();
        gA += 32; gB += 32;
    }

    float* outp = part + (size_t)kp * ((size_t)NN * DH);
#pragma unroll
    for (int mi = 0; mi < 4; ++mi) {
#pragma unroll
        for (int r = 0; r < 4; ++r) {
            size_t i = mbase + wm * 64 + mi * 16 + quad * 4 + r;
            float* op = outp + i * DH + wn * 64 + r16;
#pragma unroll
            for (int ni = 0; ni < 4; ++ni) op[ni * 16] = acc[mi][ni][r];
        }
    }
}

// ---- h[i][c] = rsqrt(rd[i]) * sum_p part[p][i][c]. Coalesced float4.
__global__ __launch_bounds__(256) void k_red(
    const float* __restrict__ part, const float* __restrict__ rdv,
    float* __restrict__ h)
{
    int i = blockIdx.x * 8 + (threadIdx.x >> 5);
    int c4 = (threadIdx.x & 31) * 4;
    size_t off = (size_t)i * DH + c4;
    float4 s = (float4){0.f, 0.f, 0.f, 0.f};
#pragma unroll
    for (int p = 0; p < SPLITK; ++p) {
        float4 v = *(const float4*)(part + (size_t)p * ((size_t)NN * DH) + off);
        s.x += v.x; s.y += v.y; s.z += v.z; s.w += v.w;
    }
    float sc = rsqrtf(rdv[i]);
    s.x *= sc; s.y *= sc; s.z *= sc; s.w *= sc;
    *(float4*)(h + off) = s;
}

// ---- per-graph max over 128 rows of h (4MB) + 16-class linear. grid 64.
__global__ __launch_bounds__(256) void k_poolcls(
    const float* __restrict__ h, const float* __restrict__ wc,
    const float* __restrict__ bc, float* __restrict__ out)
{
    __shared__ float red[256];
    __shared__ float pooled[128];
    int g = blockIdx.x;
    int c = threadIdx.x & 127, rh = threadIdx.x >> 7;
    float mx = -1e30f;
#pragma unroll 8
    for (int r = 0; r < 64; ++r) {
        int i = g * 128 + rh * 64 + r;
        mx = fmaxf(mx, h[(size_t)i * DH + c]);
    }
    red[threadIdx.x] = mx;
    __syncthreads();
    if (rh == 0) pooled[c] = fmaxf(red[c], red[c + 128]);
    __syncthreads();
    if (threadIdx.x < NCLS) {
        float a = bc[threadIdx.x];
        const float* wr = wc + threadIdx.x * 128;
#pragma unroll 8
        for (int k = 0; k < 128; ++k) a += pooled[k] * wr[k];
        out[g * NCLS + threadIdx.x] = a;
    }
}

extern "C" void kernel_launch(void* const* d_in, const int* in_sizes, int n_in,
                              void* d_out, int out_size, void* d_ws, size_t ws_size,
                              hipStream_t stream)
{
    const int*   x   = (const int*)  d_in[0];
    const float* m   = (const float*)d_in[1];
    // d_in[2] = bm: (i*64)//8192 -> 128 consecutive rows per graph (fixed by setup)
    const float* emb = (const float*)d_in[3];
    const float* w1  = (const float*)d_in[4];
    const float* b1  = (const float*)d_in[5];
    const float* w2  = (const float*)d_in[6];
    const float* b2  = (const float*)d_in[7];
    const float* wc  = (const float*)d_in[8];
    const float* bc  = (const float*)d_in[9];
    float* out = (float*)d_out;

    char* ws = (char*)d_ws;
    unsigned short* mb = (unsigned short*)ws;                         // 128 MB
    float* rd   = (float*)(ws + (size_t)134217728);                   // 32 KB
    float* cd   = rd + NN;                                            // 32 KB
    unsigned short* msgT = (unsigned short*)(cd + NN);                // 2 MB
    float* part = (float*)((char*)msgT + (size_t)2 * NN * DH);        // 32 MB
    float* cdpart = part;      // aliased (16 MB): consumed before first k_gemm
    float* h    = part + (size_t)SPLITK * NN * DH;                    // 4 MB

    k_castcd<<<NN / 16, 256, 0, stream>>>(m, mb, rd, cdpart);
    k_cd2<<<NN / 32, 256, 0, stream>>>(cdpart, cd);
    k_msg<<<NN / 16, 128, 0, stream>>>(x, emb, nullptr, w1, b1, cd, msgT, 1);
    k_gemm<<<64 * SPLITK, 256, 0, stream>>>(mb, msgT, part);
    k_red<<<NN / 8, 256, 0, stream>>>(part, rd, h);
    k_msg<<<NN / 16, 128, 0, stream>>>(nullptr, nullptr, h, w2, b2, cd, msgT, 2);
    k_gemm<<<64 * SPLITK, 256, 0, stream>>>(mb, msgT, part);
    k_red<<<NN / 8, 256, 0, stream>>>(part, rd, h);
    k_poolcls<<<NGRAPH, 256, 0, stream>>>(h, wc, bc, out);
}

// Round 3
// 520.599 us; speedup vs baseline: 1.1333x; 1.0308x over previous
//
#include <hip/hip_runtime.h>
#include <stdint.h>

// GCN pipeline on MI355X. Factorization:
//   (m/deg)@msg = diag(rsqrt(rd)) * m_bf16 @ (diag(rsqrt(cd))*msg)
// R6: k_gemm BK 32->64: stage two K-steps per barrier round (16 rounds not 32,
// 32KB in flight/block, 32 MFMA/round/wave to hide each vmcnt drain). Fragment
// reads use T2-style XOR chunk swizzle (pre-swizzled GLOBAL source + swizzled
// ds_read; LDS dest linear, rule #21) to keep ds_read_b128 conflict-free.
// All other kernels frozen from R5.
//   k_castcd   : m fp32 -> mb bf16, rd row sums, cdpart col partials (512 slabs)
//   k_cd2      : reduce 512 slabs -> cd
//   k_msg      : msgT[n][j] = bf16(relu(src[j]@W[n]+b[n]) * rsqrt(cd[j]))  (MFMA)
//   k_gemm     : split-K=8 bf16 MFMA GEMM, BK=64, global_load_lds w16
//   k_red      : h[i][:] = rsqrt(rd[i]) * sum_p part[p][i][:]   (coalesced)
//   k_poolcls  : per-graph max over h + 16-class linear

#define NN 8192
#define DH 128
#define NCLS 16
#define NGRAPH 64
#define SPLITK 8
#define KCHUNK (NN / SPLITK) // 1024

typedef float floatx4 __attribute__((ext_vector_type(4)));
typedef __bf16 bf16x8 __attribute__((ext_vector_type(8)));

__device__ __forceinline__ unsigned f2bf_bits(float f) {
    union { float f; unsigned u; } v; v.f = f;
    unsigned u = v.u;
    u += 0x7fffu + ((u >> 16) & 1u);   // RNE
    return u >> 16;
}

__device__ __forceinline__ void gload16(const void* g, void* l) {
    __builtin_amdgcn_global_load_lds(
        (const __attribute__((address_space(1))) void*)g,
        (__attribute__((address_space(3))) void*)l, 16, 0, 0);
}

// ---- m fp32 -> mb bf16, rd row sums, col partial sums. Block = 16 rows.
__global__ __launch_bounds__(256) void k_castcd(
    const float* __restrict__ m, unsigned short* __restrict__ mb,
    float* __restrict__ rd, float* __restrict__ cdpart)
{
    __shared__ float red[256][17];
    int t = threadIdx.x;
    int rb = blockIdx.x;             // rows rb*16 .. +15
    float cs[32];
#pragma unroll
    for (int u = 0; u < 32; ++u) cs[u] = 0.f;

    for (int r = 0; r < 16; ++r) {
        const float* src = m + ((size_t)rb * 16 + r) * NN;
        unsigned short* dst = mb + ((size_t)rb * 16 + r) * NN;
        float rsum = 0.f;
#pragma unroll
        for (int it = 0; it < 8; ++it) {
            int c = it * 1024 + t * 4;
            float4 a = *(const float4*)(src + c);
            rsum += (a.x + a.y) + (a.z + a.w);
            cs[it * 4 + 0] += a.x; cs[it * 4 + 1] += a.y;
            cs[it * 4 + 2] += a.z; cs[it * 4 + 3] += a.w;
            uint2 o;
            o.x = f2bf_bits(a.x) | (f2bf_bits(a.y) << 16);
            o.y = f2bf_bits(a.z) | (f2bf_bits(a.w) << 16);
            *(uint2*)(dst + c) = o;
        }
        red[t][r] = rsum;
    }
#pragma unroll
    for (int it = 0; it < 8; ++it) {
        float4 o = (float4){cs[it * 4], cs[it * 4 + 1], cs[it * 4 + 2], cs[it * 4 + 3]};
        *(float4*)(cdpart + (size_t)rb * NN + it * 1024 + t * 4) = o;
    }
    __syncthreads();
    if (t < 16) {
        float s = 0.f;
#pragma unroll 8
        for (int u = 0; u < 256; ++u) s += red[u][t];
        rd[rb * 16 + t] = s;
    }
}

// ---- reduce 512 col-partial slabs -> cd.
__global__ __launch_bounds__(256) void k_cd2(
    const float* __restrict__ cdpart, float* __restrict__ cd)
{
    __shared__ float p2[8][33];
    int c = threadIdx.x & 31, g = threadIdx.x >> 5;
    int col = blockIdx.x * 32 + c;
    float s = 0.f;
#pragma unroll 8
    for (int r = 0; r < 64; ++r)
        s += cdpart[(size_t)(g * 64 + r) * NN + col];
    p2[g][c] = s;
    __syncthreads();
    if (threadIdx.x < 32) {
        float a = 0.f;
#pragma unroll
        for (int u = 0; u < 8; ++u) a += p2[u][threadIdx.x];
        cd[blockIdx.x * 32 + threadIdx.x] = a;
    }
}

// ---- msgT[n][j] = bf16( relu( src[j]@W[n] + b[n] ) * rsqrt(cd[j]) )
__global__ __launch_bounds__(128) void k_msg(
    const int* __restrict__ x, const float* __restrict__ emb,
    const float* __restrict__ hsrc,
    const float* __restrict__ w, const float* __restrict__ bias,
    const float* __restrict__ cdv, unsigned short* __restrict__ msgT,
    int layer)
{
    int wv = threadIdx.x >> 6;
    int lane = threadIdx.x & 63;
    int quad = lane >> 4, r16 = lane & 15;
    int j = blockIdx.x * 16 + r16;

    floatx4 acc[4];
#pragma unroll
    for (int t = 0; t < 4; ++t) acc[t] = (floatx4)0.f;

    const float* src;
    if (layer == 1) src = emb + (size_t)x[j] * DH;
    else            src = hsrc + (size_t)j * DH;

#pragma unroll
    for (int e0 = 0; e0 < DH; e0 += 32) {
        int ke = e0 + quad * 8;
        float4 a = *(const float4*)(src + ke);
        float4 b = *(const float4*)(src + ke + 4);
        bf16x8 bfv;
        bfv[0] = (__bf16)a.x; bfv[1] = (__bf16)a.y; bfv[2] = (__bf16)a.z; bfv[3] = (__bf16)a.w;
        bfv[4] = (__bf16)b.x; bfv[5] = (__bf16)b.y; bfv[6] = (__bf16)b.z; bfv[7] = (__bf16)b.w;
#pragma unroll
        for (int tt = 0; tt < 4; ++tt) {
            int t = wv * 4 + tt;
            const float* wp = w + (size_t)(t * 16 + r16) * DH + ke;
            float4 wa = *(const float4*)wp;
            float4 wb = *(const float4*)(wp + 4);
            bf16x8 af;
            af[0] = (__bf16)wa.x; af[1] = (__bf16)wa.y; af[2] = (__bf16)wa.z; af[3] = (__bf16)wa.w;
            af[4] = (__bf16)wb.x; af[5] = (__bf16)wb.y; af[6] = (__bf16)wb.z; af[7] = (__bf16)wb.w;
            acc[tt] = __builtin_amdgcn_mfma_f32_16x16x32_bf16(af, bfv, acc[tt], 0, 0, 0);
        }
    }
    float cs = rsqrtf(cdv[j]);
#pragma unroll
    for (int tt = 0; tt < 4; ++tt) {
#pragma unroll
        for (int r = 0; r < 4; ++r) {
            int n = (wv * 4 + tt) * 16 + quad * 4 + r;
            float val = acc[tt][r] + bias[n];
            val = fmaxf(val, 0.f) * cs;
            msgT[(size_t)n * NN + j] = (unsigned short)f2bf_bits(val);
        }
    }
}

// ---- part[kp][i][n] = sum_{k in chunk kp} A[i][k] * Bt[n][k]
// BM=128, BN=128, BK=64, 4 waves of 64x64. Single-buffer, one stage+drain per
// 64-wide K-step (16 rounds). LDS tile [128 rows][128 B]; 16B chunk c of row r
// holds global chunk c^(r&7) (XOR swizzle, applied at global src AND ds_read).
__global__ __launch_bounds__(256) void k_gemm(
    const unsigned short* __restrict__ A,   // 8192 x 8192 bf16 row-major
    const unsigned short* __restrict__ Bt,  // 128 x 8192 bf16 (N x K)
    float* __restrict__ part)               // SPLITK x 8192 x 128
{
    __shared__ unsigned short lA[128 * 64];  // 16 KB
    __shared__ unsigned short lB[128 * 64];  // 16 KB
    int mblk = blockIdx.x & 63;
    int kp = blockIdx.x >> 6;
    int tid = threadIdx.x;
    int wv = tid >> 6, lane = tid & 63;
    int quad = lane >> 4, r16 = lane & 15;
    int wm = wv >> 1, wn = wv & 1;
    size_t mbase = (size_t)mblk * 128;
    int kbase = kp * KCHUNK;

    floatx4 acc[4][4];
#pragma unroll
    for (int mi = 0; mi < 4; ++mi)
#pragma unroll
        for (int ni = 0; ni < 4; ++ni) acc[mi][ni] = (floatx4)0.f;

    // staging lanes: srow 0..7 selects row within 8-row group, kq 16B chunk 0..7.
    // Global chunk fetched = kq ^ srow (so LDS slot kq of row holds chunk kq^(row&7)).
    int srow = lane >> 3;            // 0..7
    int kq = (lane & 7) ^ srow;      // swizzled global 16B-chunk index
    const unsigned short* gA = A + (mbase + wv * 32 + srow) * (size_t)NN + kbase + kq * 8;
    const unsigned short* gB = Bt + (size_t)(wv * 32 + srow) * NN + kbase + kq * 8;
    char* lAw = (char*)lA + wv * 4096;
    char* lBw = (char*)lB + wv * 4096;

    for (int it = 0; it < KCHUNK / 64; ++it) {
#pragma unroll
        for (int jj = 0; jj < 4; ++jj) {   // 8 rows per instruction
            gload16(gA + (size_t)(8 * jj) * NN, lAw + jj * 1024);
            gload16(gB + (size_t)(8 * jj) * NN, lBw + jj * 1024);
        }
        __syncthreads();
#pragma unroll
        for (int ks = 0; ks < 2; ++ks) {
            bf16x8 af[4], bf[4];
#pragma unroll
            for (int mi = 0; mi < 4; ++mi) {
                int row = wm * 64 + mi * 16 + r16;
                int ch = (ks * 4 + quad) ^ (r16 & 7);
                af[mi] = *(const bf16x8*)((const char*)lA + (row * 128 + ch * 16));
            }
#pragma unroll
            for (int ni = 0; ni < 4; ++ni) {
                int row = wn * 64 + ni * 16 + r16;
                int ch = (ks * 4 + quad) ^ (r16 & 7);
                bf[ni] = *(const bf16x8*)((const char*)lB + (row * 128 + ch * 16));
            }
#pragma unroll
            for (int mi = 0; mi < 4; ++mi)
#pragma unroll
                for (int ni = 0; ni < 4; ++ni)
                    acc[mi][ni] = __builtin_amdgcn_mfma_f32_16x16x32_bf16(af[mi], bf[ni], acc[mi][ni], 0, 0, 0);
        }
        __syncthreads();
        gA += 64; gB += 64;
    }

    float* outp = part + (size_t)kp * ((size_t)NN * DH);
#pragma unroll
    for (int mi = 0; mi < 4; ++mi) {
#pragma unroll
        for (int r = 0; r < 4; ++r) {
            size_t i = mbase + wm * 64 + mi * 16 + quad * 4 + r;
            float* op = outp + i * DH + wn * 64 + r16;
#pragma unroll
            for (int ni = 0; ni < 4; ++ni) op[ni * 16] = acc[mi][ni][r];
        }
    }
}

// ---- h[i][c] = rsqrt(rd[i]) * sum_p part[p][i][c]. Coalesced float4.
__global__ __launch_bounds__(256) void k_red(
    const float* __restrict__ part, const float* __restrict__ rdv,
    float* __restrict__ h)
{
    int i = blockIdx.x * 8 + (threadIdx.x >> 5);
    int c4 = (threadIdx.x & 31) * 4;
    size_t off = (size_t)i * DH + c4;
    float4 s = (float4){0.f, 0.f, 0.f, 0.f};
#pragma unroll
    for (int p = 0; p < SPLITK; ++p) {
        float4 v = *(const float4*)(part + (size_t)p * ((size_t)NN * DH) + off);
        s.x += v.x; s.y += v.y; s.z += v.z; s.w += v.w;
    }
    float sc = rsqrtf(rdv[i]);
    s.x *= sc; s.y *= sc; s.z *= sc; s.w *= sc;
    *(float4*)(h + off) = s;
}

// ---- per-graph max over 128 rows of h + 16-class linear. grid 64.
__global__ __launch_bounds__(256) void k_poolcls(
    const float* __restrict__ h, const float* __restrict__ wc,
    const float* __restrict__ bc, float* __restrict__ out)
{
    __shared__ float red[256];
    __shared__ float pooled[128];
    int g = blockIdx.x;
    int c = threadIdx.x & 127, rh = threadIdx.x >> 7;
    float mx = -1e30f;
#pragma unroll 8
    for (int r = 0; r < 64; ++r) {
        int i = g * 128 + rh * 64 + r;
        mx = fmaxf(mx, h[(size_t)i * DH + c]);
    }
    red[threadIdx.x] = mx;
    __syncthreads();
    if (rh == 0) pooled[c] = fmaxf(red[c], red[c + 128]);
    __syncthreads();
    if (threadIdx.x < NCLS) {
        float a = bc[threadIdx.x];
        const float* wr = wc + threadIdx.x * 128;
#pragma unroll 8
        for (int k = 0; k < 128; ++k) a += pooled[k] * wr[k];
        out[g * NCLS + threadIdx.x] = a;
    }
}

extern "C" void kernel_launch(void* const* d_in, const int* in_sizes, int n_in,
                              void* d_out, int out_size, void* d_ws, size_t ws_size,
                              hipStream_t stream)
{
    const int*   x   = (const int*)  d_in[0];
    const float* m   = (const float*)d_in[1];
    // d_in[2] = bm: (i*64)//8192 -> 128 consecutive rows per graph (fixed by setup)
    const float* emb = (const float*)d_in[3];
    const float* w1  = (const float*)d_in[4];
    const float* b1  = (const float*)d_in[5];
    const float* w2  = (const float*)d_in[6];
    const float* b2  = (const float*)d_in[7];
    const float* wc  = (const float*)d_in[8];
    const float* bc  = (const float*)d_in[9];
    float* out = (float*)d_out;

    char* ws = (char*)d_ws;
    unsigned short* mb = (unsigned short*)ws;                         // 128 MB
    float* rd   = (float*)(ws + (size_t)134217728);                   // 32 KB
    float* cd   = rd + NN;                                            // 32 KB
    unsigned short* msgT = (unsigned short*)(cd + NN);                // 2 MB
    float* part = (float*)((char*)msgT + (size_t)2 * NN * DH);        // 32 MB
    float* cdpart = part;      // aliased (16 MB): consumed before first k_gemm
    float* h    = part + (size_t)SPLITK * NN * DH;                    // 4 MB

    k_castcd<<<NN / 16, 256, 0, stream>>>(m, mb, rd, cdpart);
    k_cd2<<<NN / 32, 256, 0, stream>>>(cdpart, cd);
    k_msg<<<NN / 16, 128, 0, stream>>>(x, emb, nullptr, w1, b1, cd, msgT, 1);
    k_gemm<<<64 * SPLITK, 256, 0, stream>>>(mb, msgT, part);
    k_red<<<NN / 8, 256, 0, stream>>>(part, rd, h);
    k_msg<<<NN / 16, 128, 0, stream>>>(nullptr, nullptr, h, w2, b2, cd, msgT, 2);
    k_gemm<<<64 * SPLITK, 256, 0, stream>>>(mb, msgT, part);
    k_red<<<NN / 8, 256, 0, stream>>>(part, rd, h);
    k_poolcls<<<NGRAPH, 256, 0, stream>>>(h, wc, bc, out);
}